// Round 6
// baseline (217.907 us; speedup 1.0000x reference)
//
#include <hip/hip_runtime.h>

constexpr int N_NODES  = 100000;
constexpr int N_EDGES  = 3200000;
constexpr int N_GRAPHS = 64;

constexpr int BSHIFT  = 7;                               // 128 nodes per bin
constexpr int BMASK   = 127;
constexpr int NBINS   = (N_NODES + BMASK) >> BSHIFT;     // 782
constexpr int BIN_CAP = 4608;                            // mean 4092, +8 sigma
constexpr int SRC_BITS = 17;                             // 100000 < 2^17
constexpr int SRC_MASK = (1 << SRC_BITS) - 1;

constexpr int NB_BIN  = 512;                             // exactly 2 blocks/CU
constexpr int EPB     = N_EDGES / NB_BIN;                // 6250
constexpr int EPT     = (EPB + 1023) / 1024;             // 7 edges/thread max

// ================= counting-sort CSR build =================

// Pass 1: bucket edges by dst>>7. dst read ONCE (register-cached between
// phases); per-edge atomics are LDS; one global atomic per (block,bin)
// reserves space; payload packed to 4B: (dst&127)<<17 | src.
__global__ __launch_bounds__(1024) void bin_kernel(
        const int* __restrict__ src, const int* __restrict__ dst,
        int* __restrict__ bin_cur, int* __restrict__ binned) {
    __shared__ int hist[NBINS];
    __shared__ int base[NBINS];
    int tid = threadIdx.x;
    int e0 = blockIdx.x * EPB;
    int e1 = e0 + EPB;                     // NB_BIN*EPB == N_EDGES exactly
    if (tid < NBINS) hist[tid] = 0;
    __syncthreads();
    int dc[EPT];
#pragma unroll
    for (int k = 0; k < EPT; ++k) {
        int e = e0 + tid + k * 1024;
        if (e < e1) {
            int d = dst[e];
            dc[k] = d;
            atomicAdd(&hist[d >> BSHIFT], 1);
        }
    }
    __syncthreads();
    if (tid < NBINS) {
        int h = hist[tid];
        base[tid] = h ? atomicAdd(&bin_cur[tid], h) : 0;
        hist[tid] = 0;                     // reset for ranking
    }
    __syncthreads();
#pragma unroll
    for (int k = 0; k < EPT; ++k) {
        int e = e0 + tid + k * 1024;
        if (e < e1) {
            int d = dc[k];
            int b = d >> BSHIFT;
            int r = base[b] + atomicAdd(&hist[b], 1);
            if (r < BIN_CAP)
                binned[(size_t)b * BIN_CAP + r] = ((d & BMASK) << SRC_BITS) | src[e];
        }
    }
}

// exclusive scan of bin sizes -> bin_base (782 values, one 1024-thread block)
__global__ __launch_bounds__(1024) void binscan_kernel(
        const int* __restrict__ bin_cur, int* __restrict__ bin_base,
        int* __restrict__ rowptr) {
    __shared__ int s[1024];
    int t = threadIdx.x;
    int v = (t < NBINS) ? bin_cur[t] : 0;
    s[t] = v;
    __syncthreads();
    for (int o = 1; o < 1024; o <<= 1) {
        int x = (t >= o) ? s[t - o] : 0;
        __syncthreads();
        s[t] += x;
        __syncthreads();
    }
    if (t < NBINS) bin_base[t] = s[t] - v;
    if (t == 0) rowptr[N_NODES] = N_EDGES;
}

// Pass 2: one block per 128-node bin. LDS count -> dis + rowptr; LDS rank ->
// csr scatter confined to the bin's ~16KB segment.
__global__ __launch_bounds__(512) void csrbuild_kernel(
        const int* __restrict__ binned, const int* __restrict__ bin_cur,
        const int* __restrict__ bin_base, int* __restrict__ rowptr,
        float* __restrict__ dis, int* __restrict__ csr) {
    __shared__ int cnt[128];
    __shared__ int lofs[128];
    __shared__ int s[128];
    int b = blockIdx.x;
    int t = threadIdx.x;
    int size  = min(bin_cur[b], BIN_CAP);
    int gbase = bin_base[b];
    const int* bp = binned + (size_t)b * BIN_CAP;
    if (t < 128) cnt[t] = 0;
    __syncthreads();
    for (int i = t; i < size; i += 512) atomicAdd(&cnt[bp[i] >> SRC_BITS], 1);
    __syncthreads();
    if (t < 128) {
        int n = (b << BSHIFT) + t;
        int deg = cnt[t];
        if (n < N_NODES) dis[n] = 1.0f / sqrtf((float)deg + 1.0f);  // +1 self loop
        s[t] = deg;
    }
    __syncthreads();
    for (int o = 1; o < 128; o <<= 1) {
        int x = 0;
        if (t < 128 && t >= o) x = s[t - o];
        __syncthreads();
        if (t < 128) s[t] += x;
        __syncthreads();
    }
    if (t < 128) {
        int n = (b << BSHIFT) + t;
        int excl = s[t] - cnt[t];
        if (n < N_NODES) rowptr[n] = gbase + excl;
        lofs[t] = excl;
        cnt[t] = 0;                                   // reset for ranking
    }
    __syncthreads();
    for (int i = t; i < size; i += 512) {
        int p = bp[i];
        int ln = p >> SRC_BITS;
        int r = atomicAdd(&cnt[ln], 1);
        csr[gbase + lofs[ln] + r] = p & SRC_MASK;
    }
}

// ================= per-layer kernels =================

// xs[i,0:3] = x[i,:]*dis[i], xs[i,3] = 0   (aggregate BEFORE W1: 3-dim << 32-dim)
__global__ void pre1_kernel(const float* __restrict__ x, const float* __restrict__ dis,
                            float* __restrict__ xs) {
    int i = blockIdx.x * blockDim.x + threadIdx.x;
    if (i >= N_NODES) return;
    float d = dis[i];
    float4 v;
    v.x = x[(size_t)i * 3 + 0] * d;
    v.y = x[(size_t)i * 3 + 1] * d;
    v.z = x[(size_t)i * 3 + 2] * d;
    v.w = 0.f;
    *reinterpret_cast<float4*>(&xs[(size_t)i * 4]) = v;
}

// group of F lanes per node: acc = in[n] (self) + sum_{e: dst=n} in[src]; epilogue dis/b/relu
template<int F, bool ADD_B, bool RELU>
__global__ void gather_kernel(const float* __restrict__ in, const int* __restrict__ rowptr,
                              const int* __restrict__ csr, const float* __restrict__ dis,
                              const float* __restrict__ b, float* __restrict__ out) {
    constexpr int GPB = 256 / F;
    int tid = threadIdx.x;
    int l = tid & (F - 1);
    int n = blockIdx.x * GPB + (tid / F);
    if (n >= N_NODES) return;
    int beg = rowptr[n], end = rowptr[n + 1];
    float a0 = in[(size_t)n * F + l];   // self loop (already dis[src]-scaled)
    float a1 = 0.f, a2 = 0.f, a3 = 0.f;
    int k = beg;
    for (; k + 3 < end; k += 4) {
        int s0 = csr[k], s1 = csr[k + 1], s2 = csr[k + 2], s3 = csr[k + 3];
        a0 += in[(size_t)s0 * F + l];
        a1 += in[(size_t)s1 * F + l];
        a2 += in[(size_t)s2 * F + l];
        a3 += in[(size_t)s3 * F + l];
    }
    for (; k < end; ++k) a0 += in[(size_t)csr[k] * F + l];
    float v = ((a0 + a1) + (a2 + a3)) * dis[n];
    if (ADD_B) v += b[l];
    if (RELU) v = fmaxf(v, 0.f);
    out[(size_t)n * F + l] = v;
}

// h1[i,f] = relu( sum_k m[i,k]*W1[k,f] + b1[f] ), m is 4-padded (k<3)
__global__ void lin1_kernel(const float* __restrict__ m, const float* __restrict__ W1,
                            const float* __restrict__ b1, float* __restrict__ h1) {
    int i = blockIdx.x * blockDim.x + threadIdx.x;
    if (i >= N_NODES) return;
    float4 mv = *reinterpret_cast<const float4*>(&m[(size_t)i * 4]);
#pragma unroll
    for (int f = 0; f < 32; ++f) {
        float s = b1[f];
        s = fmaf(mv.x, W1[0 * 32 + f], s);
        s = fmaf(mv.y, W1[1 * 32 + f], s);
        s = fmaf(mv.z, W1[2 * 32 + f], s);
        h1[(size_t)i * 32 + f] = fmaxf(s, 0.f);
    }
}

// g[i,:FOUT] = (in[i,:FIN] @ W) * dis[i]
template<int FIN, int FOUT>
__global__ void lin_pre_kernel(const float* __restrict__ in, const float* __restrict__ W,
                               const float* __restrict__ dis, float* __restrict__ g) {
    int i = blockIdx.x * blockDim.x + threadIdx.x;
    if (i >= N_NODES) return;
    float xin[FIN];
#pragma unroll
    for (int k = 0; k < FIN; ++k) xin[k] = in[(size_t)i * FIN + k];
    float d = dis[i];
#pragma unroll
    for (int f = 0; f < FOUT; ++f) {
        float s = 0.f;
#pragma unroll
        for (int k = 0; k < FIN; ++k) s = fmaf(xin[k], W[k * FOUT + f], s);
        g[(size_t)i * FOUT + f] = s * d;
    }
}

// ================= pooling + final linear =================

__global__ void pool_kernel(const float* __restrict__ h, const int* __restrict__ batch,
                            float* __restrict__ pool) {
    __shared__ float lsum[N_GRAPHS * 8];
    __shared__ float lcnt[N_GRAPHS];
    int tid = threadIdx.x;
    for (int j = tid; j < N_GRAPHS * 8; j += blockDim.x) lsum[j] = 0.f;
    for (int j = tid; j < N_GRAPHS; j += blockDim.x) lcnt[j] = 0.f;
    __syncthreads();
    int i = blockIdx.x * blockDim.x + tid;
    if (i < N_NODES) {
        int gm = batch[i];
        const float4* hp = reinterpret_cast<const float4*>(&h[(size_t)i * 8]);
        float4 a = hp[0], bq = hp[1];
        atomicAdd(&lsum[gm * 8 + 0], a.x);
        atomicAdd(&lsum[gm * 8 + 1], a.y);
        atomicAdd(&lsum[gm * 8 + 2], a.z);
        atomicAdd(&lsum[gm * 8 + 3], a.w);
        atomicAdd(&lsum[gm * 8 + 4], bq.x);
        atomicAdd(&lsum[gm * 8 + 5], bq.y);
        atomicAdd(&lsum[gm * 8 + 6], bq.z);
        atomicAdd(&lsum[gm * 8 + 7], bq.w);
        atomicAdd(&lcnt[gm], 1.0f);
    }
    __syncthreads();
    for (int idx = tid; idx < N_GRAPHS * 9; idx += blockDim.x) {
        int gm = idx / 9, j = idx % 9;
        if (lcnt[gm] != 0.f) {
            if (j < 8) atomicAdd(&pool[gm * 8 + j], lsum[gm * 8 + j]);
            else       atomicAdd(&pool[512 + gm], lcnt[gm]);
        }
    }
}

__global__ void final_kernel(const float* __restrict__ pool, const float* __restrict__ Wf,
                             const float* __restrict__ bf, float* __restrict__ out) {
    int t = threadIdx.x;
    if (t >= N_GRAPHS * 3) return;
    int gm = t / 3, c = t % 3;
    float cnt = fmaxf(pool[512 + gm], 1.0f);
    float s = 0.f;
#pragma unroll
    for (int f = 0; f < 8; ++f) s = fmaf(pool[gm * 8 + f] / cnt, Wf[f * 3 + c], s);
    out[t] = s + bf[c];
}

// ================= launch =================

extern "C" void kernel_launch(void* const* d_in, const int* in_sizes, int n_in,
                              void* d_out, int out_size, void* d_ws, size_t ws_size,
                              hipStream_t stream) {
    const float* x     = (const float*)d_in[0];
    const int*   ei    = (const int*)d_in[1];
    const int*   batch = (const int*)d_in[2];
    const float* W1 = (const float*)d_in[3];
    const float* b1 = (const float*)d_in[4];
    const float* W2 = (const float*)d_in[5];
    const float* b2 = (const float*)d_in[6];
    const float* W3 = (const float*)d_in[7];
    const float* b3 = (const float*)d_in[8];
    const float* Wf = (const float*)d_in[9];
    const float* bf = (const float*)d_in[10];

    const int* src = ei;              // edge_index[0] = message sources
    const int* dst = ei + N_EDGES;    // edge_index[1] = aggregation targets

    const int N = N_NODES, E = N_EDGES;

    // workspace layout; binned region aliases activations (act extent 72N > binned)
    int*   bin_cur  = (int*)d_ws;                         // NBINS
    int*   bin_base = bin_cur + NBINS;                    // NBINS
    int*   rowptr   = bin_base + NBINS;                   // N+2
    float* dis      = (float*)(rowptr + N + 2);           // N
    int*   csr      = (int*)(dis + N);                    // E
    int*   binned   = csr + E;                            // NBINS*BIN_CAP ints (14.4MB)
    float* xs       = (float*)binned;                     // alias: 4N   } activations live
    float* m        = xs + (size_t)4 * N;                 // 4N          } only after csr
    float* h1       = m + (size_t)4 * N;                  // 32N         } is built
    float* g        = h1 + (size_t)32 * N;                // 16N
    float* h2       = g + (size_t)16 * N;                 // 16N
    float* pool     = h2 + (size_t)16 * N;                // 576
    float* h3       = xs;                                 // alias (8N), free at layer 3

    const int B = 256;
    const int NB_N = (N + B - 1) / B;

    hipMemsetAsync(bin_cur, 0, NBINS * sizeof(int), stream);
    hipMemsetAsync(pool, 0, N_GRAPHS * 9 * sizeof(float), stream);

    // CSR build: bucket sort (LDS atomics, packed 4B payload) -> scan -> per-bin CSR
    bin_kernel<<<NB_BIN, 1024, 0, stream>>>(src, dst, bin_cur, binned);
    binscan_kernel<<<1, 1024, 0, stream>>>(bin_cur, bin_base, rowptr);
    csrbuild_kernel<<<NBINS, 512, 0, stream>>>(binned, bin_cur, bin_base, rowptr, dis, csr);

    // Layer 1: aggregate in 3(4)-dim input space, then 4->32 linear (+b,relu)
    pre1_kernel<<<NB_N, B, 0, stream>>>(x, dis, xs);
    gather_kernel<4, false, false><<<(N + 63) / 64, B, 0, stream>>>(xs, rowptr, csr, dis, b1, m);
    lin1_kernel<<<NB_N, B, 0, stream>>>(m, W1, b1, h1);

    // Layer 2: 32->16 linear (*dis), gather 16, (+b2, relu)
    lin_pre_kernel<32, 16><<<NB_N, B, 0, stream>>>(h1, W2, dis, g);
    gather_kernel<16, true, true><<<(N + 15) / 16, B, 0, stream>>>(g, rowptr, csr, dis, b2, h2);

    // Layer 3: 16->8 linear (*dis), gather 8, (+b3, relu)
    lin_pre_kernel<16, 8><<<NB_N, B, 0, stream>>>(h2, W3, dis, g);
    gather_kernel<8, true, true><<<(N + 31) / 32, B, 0, stream>>>(g, rowptr, csr, dis, b3, h3);

    // Pool + final linear
    pool_kernel<<<NB_N, B, 0, stream>>>(h3, batch, pool);
    final_kernel<<<1, 256, 0, stream>>>(pool, Wf, bf, (float*)d_out);
}